// Round 7
// baseline (411.767 us; speedup 1.0000x reference)
//
#include <hip/hip_runtime.h>
#include <math.h>

typedef __attribute__((ext_vector_type(8))) short short8;   // 8 bf16 in 4 VGPRs
typedef __attribute__((ext_vector_type(4))) float f32x4;

#define NCODE  1024
#define NDIM   256
#define TLEN   4096
#define NBATCH 16
#define BT     64
#define TAU    3.0e-4f

__device__ __forceinline__ unsigned short f2bf(float f) {
  unsigned int u = __float_as_uint(f);
  u += 0x7FFFu + ((u >> 16) & 1u);          // round-to-nearest-even
  return (unsigned short)(u >> 16);
}
__device__ __forceinline__ float bf2f(unsigned short h) {
  return __uint_as_float(((unsigned int)h) << 16);
}

// Pre-split codebook into bf16 hi/lo, stored in MFMA A-fragment order:
// ushort index = ((ct*8 + ks)*64 + lane)*8 + j
// where row = ct*16 + (lane&15), k = ks*32 + (lane>>4)*8 + j
__global__ __launch_bounds__(256) void svq_prep_emb(const float* __restrict__ emb,
                                                    unsigned short* __restrict__ ehi,
                                                    unsigned short* __restrict__ elo,
                                                    unsigned int* __restrict__ ctr) {
  if (blockIdx.x == 0 && threadIdx.x == 0) *ctr = 0u;   // reset tie-list each launch
  int tid  = blockIdx.x * 256 + threadIdx.x;   // 0 .. 262143
  int j    = tid & 7;
  int lane = (tid >> 3) & 63;
  int blk  = tid >> 9;                          // ct*8 + ks
  int ct   = blk >> 3, ks = blk & 7;
  int row  = (ct << 4) | (lane & 15);
  int k    = (ks << 5) | ((lane >> 4) << 3) | j;
  float f  = emb[row * NDIM + k];
  unsigned short h = f2bf(f);
  unsigned short l = f2bf(f - bf2f(h));
  ehi[tid] = h;
  elo[tid] = l;
}

// One k-step with ci=2 blocking: transient bh/bl (8 regs), A single-buffered
// (16 regs), acc 32 regs — total live set ~90 VGPRs, fits the 128-reg granule
// the allocator insists on (R4-R6 evidence), so no scratch spill.
// Per-accumulator op order (ks ascending: hi*bh, hi*bl, lo*bh) is identical
// to the validated R5/R6 numerics — TAU margin carries over.
#define KSTEP(KS)                                                               \
  {                                                                             \
    const int kb0 = ((KS) * 32 + khalf) * 2;                                    \
    _Pragma("unroll")                                                           \
    for (int ti = 0; ti < 4; ++ti) {                                            \
      const int off = bbase + (kb0 ^ bswz) + ti * 8192;                         \
      short8 bh = *(const short8*)(xhi_s + off);                                \
      short8 bl = *(const short8*)(xlo_s + off);                                \
      _Pragma("unroll")                                                         \
      for (int ci = 0; ci < 2; ++ci) {                                          \
        acc[ci][ti] = __builtin_amdgcn_mfma_f32_16x16x32_bf16(ah[ci], bh, acc[ci][ti], 0, 0, 0); \
        acc[ci][ti] = __builtin_amdgcn_mfma_f32_16x16x32_bf16(ah[ci], bl, acc[ci][ti], 0, 0, 0); \
        acc[ci][ti] = __builtin_amdgcn_mfma_f32_16x16x32_bf16(al[ci], bh, acc[ci][ti], 0, 0, 0); \
      }                                                                         \
    }                                                                           \
    if ((KS) < 7) {                                                             \
      _Pragma("unroll")                                                         \
      for (int ci = 0; ci < 2; ++ci) {                                          \
        ah[ci] = pe_h[(ci * 8 + (KS) + 1) * 64];                                \
        al[ci] = pe_l[(ci * 8 + (KS) + 1) * 64];                                \
      }                                                                         \
    }                                                                           \
  }

__global__ __launch_bounds__(256) void svq_main(const float* __restrict__ x,
                                                const float* __restrict__ emb,
                                                const short8* __restrict__ ehi,
                                                const short8* __restrict__ elo,
                                                float* __restrict__ out,
                                                unsigned int* __restrict__ ctr,
                                                int* __restrict__ list,
                                                int cap) {
  __shared__ char smem[65536];   // x_hi [0,32K) | x_lo [32K,64K); reused by epilogue
  const int tid  = threadIdx.x;
  const int lane = tid & 63;
  const int w    = tid >> 6;                 // wave id 0..3
  const int bx   = blockIdx.x;
  const int b    = bx >> 6;                  // batch
  const int t0   = (bx & 63) * BT;           // token-tile start

  // ---- stage x tile into LDS: bf16 hi/lo, t-major rows of k, XOR bank swizzle ----
  {
    const float* xb = x + (size_t)b * NDIM * TLEN + t0;
    const int tl = lane;
    const int sw = (tl & 7) << 4;
#pragma unroll 4
    for (int it = 0; it < 16; ++it) {
      const int kb = w * 4 + it * 16;
      float v0 = xb[(size_t)(kb + 0) * TLEN + tl];
      float v1 = xb[(size_t)(kb + 1) * TLEN + tl];
      float v2 = xb[(size_t)(kb + 2) * TLEN + tl];
      float v3 = xb[(size_t)(kb + 3) * TLEN + tl];
      unsigned short h0 = f2bf(v0), h1 = f2bf(v1), h2 = f2bf(v2), h3 = f2bf(v3);
      unsigned short l0 = f2bf(v0 - bf2f(h0)), l1 = f2bf(v1 - bf2f(h1));
      unsigned short l2 = f2bf(v2 - bf2f(h2)), l3 = f2bf(v3 - bf2f(h3));
      unsigned long long ph = (unsigned long long)h0 | ((unsigned long long)h1 << 16)
                            | ((unsigned long long)h2 << 32) | ((unsigned long long)h3 << 48);
      unsigned long long pl = (unsigned long long)l0 | ((unsigned long long)l1 << 16)
                            | ((unsigned long long)l2 << 32) | ((unsigned long long)l3 << 48);
      int off = tl * 512 + ((kb * 2) ^ sw);
      *(unsigned long long*)(smem + off)         = ph;
      *(unsigned long long*)(smem + 32768 + off) = pl;
    }
  }
  __syncthreads();

  float bestv[4], secv[4];
  int   besti[4];
#pragma unroll
  for (int ti = 0; ti < 4; ++ti) {
    bestv[ti] = __builtin_inff(); secv[ti] = __builtin_inff(); besti[ti] = 0;
  }

  const char* xhi_s = smem;
  const char* xlo_s = smem + 32768;
  const int bbase = (lane & 15) * 512;        // t-row byte base (ti adds 8192)
  const int bswz  = (lane & 7) << 4;          // swizzle (ti*16 preserves t&7)
  const int khalf = (lane >> 4) << 3;         // k-subgroup within 32-k step

  // ---- main loop: wave w covers codes [w*256, w*256+256) in 8 chunks of 32 ----
  for (int cc = 0; cc < 8; ++cc) {
    const int ctb = w * 16 + cc * 2;          // base 16-code tile index
    const short8* pe_h = ehi + (size_t)ctb * 8 * 64 + lane;
    const short8* pe_l = elo + (size_t)ctb * 8 * 64 + lane;

    f32x4 acc[2][4];
#pragma unroll
    for (int ci = 0; ci < 2; ++ci)
#pragma unroll
      for (int ti = 0; ti < 4; ++ti)
        acc[ci][ti] = (f32x4){0.f, 0.f, 0.f, 0.f};

    short8 ah[2], al[2];
#pragma unroll
    for (int ci = 0; ci < 2; ++ci) {
      ah[ci] = pe_h[ci * 8 * 64];
      al[ci] = pe_l[ci * 8 * 64];
    }

    KSTEP(0) KSTEP(1) KSTEP(2) KSTEP(3)
    KSTEP(4) KSTEP(5) KSTEP(6) KSTEP(7)

    // best + second-best of eu = 2 - 2*dot, ascending code order per lane
#pragma unroll
    for (int ci = 0; ci < 2; ++ci) {
      const int cbase = (ctb + ci) * 16 + ((lane >> 4) << 2);
#pragma unroll
      for (int j = 0; j < 4; ++j) {
#pragma unroll
        for (int ti = 0; ti < 4; ++ti) {
          float eu = fmaf(-2.0f, acc[ci][ti][j], 2.0f);
          if (eu < bestv[ti])      { secv[ti] = bestv[ti]; bestv[ti] = eu; besti[ti] = cbase + j; }
          else if (eu < secv[ti])  { secv[ti] = eu; }
        }
      }
    }
  }

  __syncthreads();   // all waves done with x LDS; reuse region below

  float* red_v = (float*)smem;
  float* red_s = (float*)(smem + 1024);
  int*   red_i = (int*)(smem + 2048);
  int*   idxf  = (int*)(smem + 3072);

  // cross-lane (code-row groups) reduce, merging (best, second), tie-break lower index
#pragma unroll
  for (int ti = 0; ti < 4; ++ti) {
    float v = bestv[ti], s = secv[ti]; int ix = besti[ti];
#pragma unroll
    for (int off = 16; off < 64; off <<= 1) {
      float ov = __shfl_xor(v, off);
      float os = __shfl_xor(s, off);
      int   oi = __shfl_xor(ix, off);
      if (ov < v || (ov == v && oi < ix)) { s = fminf(v, os); v = ov; ix = oi; }
      else                                { s = fminf(s, ov); }
    }
    if (lane < 16) {
      red_v[w * 64 + ti * 16 + lane] = v;
      red_s[w * 64 + ti * 16 + lane] = s;
      red_i[w * 64 + ti * 16 + lane] = ix;
    }
  }
  __syncthreads();
  if (tid < 64) {       // cross-wave reduce
    float v = red_v[tid], s = red_s[tid]; int ix = red_i[tid];
#pragma unroll
    for (int ww = 1; ww < 4; ++ww) {
      float ov = red_v[ww * 64 + tid], os = red_s[ww * 64 + tid];
      int   oi = red_i[ww * 64 + tid];
      if (ov < v || (ov == v && oi < ix)) { s = fminf(v, os); v = ov; ix = oi; }
      else                                { s = fminf(s, ov); }
    }
    idxf[tid] = ix;
    if (s - v < TAU) {   // near-tie: np-bit-replicated rescore will overwrite this token
      unsigned int slot = atomicAdd(ctr, 1u);
      if ((int)slot < cap) list[slot] = (b << 12) | (t0 + tid);
    }
  }
  __syncthreads();

  // ---- epilogue: stage winning emb rows in LDS (rotated), write coalesced ----
  const int rt = tid >> 2, q = tid & 3;
  const int code = idxf[rt];
  __syncthreads();     // everyone has its code; safe to overwrite smem

  float* rows = (float*)smem;   // [64][256], column rotated by +row
  {
    const float4* src = (const float4*)(emb + (size_t)code * NDIM);
#pragma unroll
    for (int i = 0; i < 16; ++i) {
      float4 v = src[q + 4 * i];
      int n = 4 * (q + 4 * i);
      rows[rt * 256 + ((n + 0 + rt) & 255)] = v.x;
      rows[rt * 256 + ((n + 1 + rt) & 255)] = v.y;
      rows[rt * 256 + ((n + 2 + rt) & 255)] = v.z;
      rows[rt * 256 + ((n + 3 + rt) & 255)] = v.w;
    }
  }
  __syncthreads();
  {
    const int tl = lane;
    float* op = out + (size_t)b * NDIM * TLEN + t0 + tl;
#pragma unroll 8
    for (int i = 0; i < 64; ++i) {
      int n = w * 64 + i;
      op[(size_t)n * TLEN] = rows[tl * 256 + ((n + tl) & 255)];
    }
  }
}

// Rescore near-tied tokens by BIT-REPLICATING the numpy fp32 reference:
// per code, a SEQUENTIAL fp32 FMA chain over k ascending, then
// eu = 2.0f - 2.0f*acc, argmin first-min-wins. Reproduces the reference's
// rounding, so flagged tokens resolve to the SAME index the reference picked.
__global__ __launch_bounds__(256) void svq_rescore(const float* __restrict__ x,
                                                   const float* __restrict__ emb,
                                                   float* __restrict__ out,
                                                   const unsigned int* __restrict__ ctr,
                                                   const int* __restrict__ list,
                                                   int cap) {
  __shared__ float xs[256];
  __shared__ float bval[256];
  __shared__ int   bidx[256];
  const int tid = threadIdx.x;
  int n = (int)*ctr;
  if (n > cap) n = cap;
  for (int it = blockIdx.x; it < n; it += gridDim.x) {
    const int tok = list[it];
    const int b = tok >> 12;
    const int t = tok & (TLEN - 1);
    xs[tid] = x[(size_t)b * NDIM * TLEN + (size_t)tid * TLEN + t];
    __syncthreads();
    float bb = __builtin_inff(); int bi = 0;
#pragma unroll
    for (int c4 = 0; c4 < 4; ++c4) {
      const int c = c4 * 256 + tid;
      const float* er = emb + (size_t)c * NDIM;
      float acc = 0.0f;
#pragma unroll 8
      for (int k = 0; k < NDIM; ++k) acc = fmaf(xs[k], er[k], acc);
      float eu = 2.0f - 2.0f * acc;
      if (eu < bb) { bb = eu; bi = c; }       // per-thread codes ascend: first-min wins
    }
    bval[tid] = bb; bidx[tid] = bi;
    __syncthreads();
    for (int sft = 128; sft > 0; sft >>= 1) {
      if (tid < sft) {
        float ov = bval[tid + sft]; int oi = bidx[tid + sft];
        if (ov < bval[tid] || (ov == bval[tid] && oi < bidx[tid])) {
          bval[tid] = ov; bidx[tid] = oi;
        }
      }
      __syncthreads();
    }
    const int best = bidx[0];
    out[(size_t)b * NDIM * TLEN + (size_t)tid * TLEN + t] = emb[(size_t)best * NDIM + tid];
    __syncthreads();   // before next iteration overwrites xs/bval/bidx
  }
}

extern "C" void kernel_launch(void* const* d_in, const int* in_sizes, int n_in,
                              void* d_out, int out_size, void* d_ws, size_t ws_size,
                              hipStream_t stream) {
  (void)in_sizes; (void)n_in; (void)out_size;
  const float* x   = (const float*)d_in[0];
  const float* emb = (const float*)d_in[1];
  float* out = (float*)d_out;

  unsigned short* ehi = (unsigned short*)d_ws;                      // 512 KB
  unsigned short* elo = ehi + (size_t)NCODE * NDIM;                 // 512 KB
  unsigned int*   ctr = (unsigned int*)((char*)d_ws + (size_t)2 * NCODE * NDIM * 2);
  int*            lst = (int*)((char*)ctr + 16);

  long avail = (long)ws_size - (long)(2 * NCODE * NDIM * 2) - 16;
  int cap = avail > 0 ? (int)(avail / 4 < 65536 ? avail / 4 : 65536) : 0;

  svq_prep_emb<<<dim3((NCODE * NDIM) / 256), dim3(256), 0, stream>>>(emb, ehi, elo, ctr);
  svq_main<<<dim3(NBATCH * (TLEN / BT)), dim3(256), 0, stream>>>(
      x, emb, (const short8*)ehi, (const short8*)elo, out, ctr, lst, cap);
  svq_rescore<<<dim3(1024), dim3(256), 0, stream>>>(x, emb, out, ctr, lst, cap);
}

// Round 8
// 262.419 us; speedup vs baseline: 1.5691x; 1.5691x over previous
//
#include <hip/hip_runtime.h>
#include <math.h>

typedef __attribute__((ext_vector_type(8))) short short8;   // 8 bf16 in 4 VGPRs
typedef __attribute__((ext_vector_type(4))) float f32x4;

#define NCODE  1024
#define NDIM   256
#define TLEN   4096
#define NBATCH 16
#define BT     64
#define TAU    2.5e-2f

__device__ __forceinline__ unsigned short f2bf(float f) {
  unsigned int u = __float_as_uint(f);
  u += 0x7FFFu + ((u >> 16) & 1u);          // round-to-nearest-even
  return (unsigned short)(u >> 16);
}

// Pre-split codebook into bf16 (hi only), MFMA A-fragment order, and also
// emit emb^T (fp32, [dim][code]) for the coalesced exact rescore.
// ushort index = ((ct*8 + ks)*64 + lane)*8 + j
// where row = ct*16 + (lane&15), k = ks*32 + (lane>>4)*8 + j
__global__ __launch_bounds__(256) void svq_prep_emb(const float* __restrict__ emb,
                                                    unsigned short* __restrict__ ehi,
                                                    float* __restrict__ embT,
                                                    unsigned int* __restrict__ ctr) {
  if (blockIdx.x == 0 && threadIdx.x == 0) *ctr = 0u;   // reset tie-list each launch
  int tid  = blockIdx.x * 256 + threadIdx.x;   // 0 .. 262143
  int j    = tid & 7;
  int lane = (tid >> 3) & 63;
  int blk  = tid >> 9;                          // ct*8 + ks
  int ct   = blk >> 3, ks = blk & 7;
  int row  = (ct << 4) | (lane & 15);
  int k    = (ks << 5) | ((lane >> 4) << 3) | j;
  float f  = emb[row * NDIM + k];
  ehi[tid] = f2bf(f);
  embT[(size_t)k * NCODE + row] = f;
}

// One k-step, single-bf16, ci=4 blocking: 4 ds_read_b128 + 16 MFMA.
// A single-buffered, reloaded after the MFMAs (regs reusable). All indices
// compile-time constants (rule #20).
#define KSTEP(KS)                                                               \
  {                                                                             \
    const int kb0 = ((KS) * 32 + khalf) * 2;                                    \
    _Pragma("unroll")                                                           \
    for (int ti = 0; ti < 4; ++ti) {                                            \
      const int off = bbase + (kb0 ^ bswz) + ti * 8192;                         \
      short8 bh = *(const short8*)(xhi_s + off);                                \
      _Pragma("unroll")                                                         \
      for (int ci = 0; ci < 4; ++ci)                                            \
        acc[ci][ti] = __builtin_amdgcn_mfma_f32_16x16x32_bf16(ah[ci], bh, acc[ci][ti], 0, 0, 0); \
    }                                                                           \
    if ((KS) < 7) {                                                             \
      _Pragma("unroll")                                                         \
      for (int ci = 0; ci < 4; ++ci)                                            \
        ah[ci] = pe_h[(ci * 8 + (KS) + 1) * 64];                                \
    }                                                                           \
  }

// 32 KB LDS -> up to 5 blocks/CU by LDS; (256,4) caps VGPR at 128 -> 4
// blocks/CU resident (16 waves). Live set ~110 regs fits 128: no spill.
__global__ __launch_bounds__(256, 4) void svq_main(const float* __restrict__ x,
                                                   const float* __restrict__ emb,
                                                   const short8* __restrict__ ehi,
                                                   float* __restrict__ out,
                                                   unsigned int* __restrict__ ctr,
                                                   int* __restrict__ list,
                                                   int cap) {
  __shared__ char smem[32768];   // x_hi [64 t][512 B]; reused by reduce+epilogue
  const int tid  = threadIdx.x;
  const int lane = tid & 63;
  const int w    = tid >> 6;                 // wave id 0..3
  const int bx   = blockIdx.x;
  const int b    = bx >> 6;                  // batch
  const int t0   = (bx & 63) * BT;           // token-tile start

  // ---- stage x tile into LDS: bf16 hi, t-major rows of k, XOR bank swizzle ----
  {
    const float* xb = x + (size_t)b * NDIM * TLEN + t0;
    const int tl = lane;
    const int sw = (tl & 7) << 4;
#pragma unroll 4
    for (int it = 0; it < 16; ++it) {
      const int kb = w * 4 + it * 16;
      float v0 = xb[(size_t)(kb + 0) * TLEN + tl];
      float v1 = xb[(size_t)(kb + 1) * TLEN + tl];
      float v2 = xb[(size_t)(kb + 2) * TLEN + tl];
      float v3 = xb[(size_t)(kb + 3) * TLEN + tl];
      unsigned short h0 = f2bf(v0), h1 = f2bf(v1), h2 = f2bf(v2), h3 = f2bf(v3);
      unsigned long long ph = (unsigned long long)h0 | ((unsigned long long)h1 << 16)
                            | ((unsigned long long)h2 << 32) | ((unsigned long long)h3 << 48);
      *(unsigned long long*)(smem + tl * 512 + ((kb * 2) ^ sw)) = ph;
    }
  }
  __syncthreads();

  float bestv[4], secv[4];
  int   besti[4];
#pragma unroll
  for (int ti = 0; ti < 4; ++ti) {
    bestv[ti] = __builtin_inff(); secv[ti] = __builtin_inff(); besti[ti] = 0;
  }

  const char* xhi_s = smem;
  const int bbase = (lane & 15) * 512;        // t-row byte base (ti adds 8192)
  const int bswz  = (lane & 7) << 4;          // swizzle (ti*16 preserves t&7)
  const int khalf = (lane >> 4) << 3;         // k-subgroup within 32-k step

  // ---- main loop: wave w covers codes [w*256, w*256+256) in 4 chunks of 64 ----
  for (int cc = 0; cc < 4; ++cc) {
    const int ctb = w * 16 + cc * 4;          // base 16-code tile index
    const short8* pe_h = ehi + (size_t)ctb * 8 * 64 + lane;

    f32x4 acc[4][4];
#pragma unroll
    for (int ci = 0; ci < 4; ++ci)
#pragma unroll
      for (int ti = 0; ti < 4; ++ti)
        acc[ci][ti] = (f32x4){0.f, 0.f, 0.f, 0.f};

    short8 ah[4];
#pragma unroll
    for (int ci = 0; ci < 4; ++ci) ah[ci] = pe_h[ci * 8 * 64];

    KSTEP(0) KSTEP(1) KSTEP(2) KSTEP(3)
    KSTEP(4) KSTEP(5) KSTEP(6) KSTEP(7)

    // best + second-best of eu = 2 - 2*dot, ascending code order per lane
#pragma unroll
    for (int ci = 0; ci < 4; ++ci) {
      const int cbase = (ctb + ci) * 16 + ((lane >> 4) << 2);
#pragma unroll
      for (int j = 0; j < 4; ++j) {
#pragma unroll
        for (int ti = 0; ti < 4; ++ti) {
          float eu = fmaf(-2.0f, acc[ci][ti][j], 2.0f);
          if (eu < bestv[ti])      { secv[ti] = bestv[ti]; bestv[ti] = eu; besti[ti] = cbase + j; }
          else if (eu < secv[ti])  { secv[ti] = eu; }
        }
      }
    }
  }

  __syncthreads();   // all waves done with x LDS; reuse region below

  float* red_v = (float*)smem;
  float* red_s = (float*)(smem + 1024);
  int*   red_i = (int*)(smem + 2048);
  int*   idxf  = (int*)(smem + 3072);

  // cross-lane (code-row groups) reduce, merging (best, second), tie-break lower index
#pragma unroll
  for (int ti = 0; ti < 4; ++ti) {
    float v = bestv[ti], s = secv[ti]; int ix = besti[ti];
#pragma unroll
    for (int off = 16; off < 64; off <<= 1) {
      float ov = __shfl_xor(v, off);
      float os = __shfl_xor(s, off);
      int   oi = __shfl_xor(ix, off);
      if (ov < v || (ov == v && oi < ix)) { s = fminf(v, os); v = ov; ix = oi; }
      else                                { s = fminf(s, ov); }
    }
    if (lane < 16) {
      red_v[w * 64 + ti * 16 + lane] = v;
      red_s[w * 64 + ti * 16 + lane] = s;
      red_i[w * 64 + ti * 16 + lane] = ix;
    }
  }
  __syncthreads();
  if (tid < 64) {       // cross-wave reduce
    float v = red_v[tid], s = red_s[tid]; int ix = red_i[tid];
#pragma unroll
    for (int ww = 1; ww < 4; ++ww) {
      float ov = red_v[ww * 64 + tid], os = red_s[ww * 64 + tid];
      int   oi = red_i[ww * 64 + tid];
      if (ov < v || (ov == v && oi < ix)) { s = fminf(v, os); v = ov; ix = oi; }
      else                                { s = fminf(s, ov); }
    }
    idxf[tid] = ix;
    if (s - v < TAU) {   // near-tie: np-bit-replicated rescore will overwrite this token
      unsigned int slot = atomicAdd(ctr, 1u);
      if ((int)slot < cap) list[slot] = (b << 12) | (t0 + tid);
    }
  }
  __syncthreads();

  // ---- epilogue: winning emb rows via LDS (rotated), 2 dim-halves of 128 ----
  const int rt = tid >> 2, q = tid & 3;      // rt = token 0..63, q = quarter
  const int code = idxf[rt];
  __syncthreads();     // everyone has its code; safe to overwrite smem

  float* rows = (float*)smem;   // [64][128] f32, column rotated by +rt
  const float4* src = (const float4*)(emb + (size_t)code * NDIM);
  for (int h = 0; h < 2; ++h) {
#pragma unroll
    for (int i = 0; i < 8; ++i) {
      float4 v = src[h * 32 + q + 4 * i];
      int n = 4 * (q + 4 * i);               // 0..127 within half
      rows[rt * 128 + ((n + 0 + rt) & 127)] = v.x;
      rows[rt * 128 + ((n + 1 + rt) & 127)] = v.y;
      rows[rt * 128 + ((n + 2 + rt) & 127)] = v.z;
      rows[rt * 128 + ((n + 3 + rt) & 127)] = v.w;
    }
    __syncthreads();
    {
      float* op = out + (size_t)b * NDIM * TLEN + (size_t)h * 128 * TLEN + t0 + lane;
#pragma unroll 8
      for (int i = 0; i < 32; ++i) {
        int n = w * 32 + i;                  // 0..127 within half
        op[(size_t)n * TLEN] = rows[lane * 128 + ((n + lane) & 127)];
      }
    }
    __syncthreads();
  }
}

// Rescore near-tied tokens by BIT-REPLICATING the numpy fp32 reference:
// per (code, token), a SEQUENTIAL fp32 FMA chain over k ascending, then
// eu = 2.0f - 2.0f*acc, argmin first-min-wins (validated in R3). Batched
// 8 tokens/block; embT gives coalesced fp32 reads.
__global__ __launch_bounds__(256) void svq_rescore(const float* __restrict__ x,
                                                   const float* __restrict__ emb,
                                                   const float* __restrict__ embT,
                                                   float* __restrict__ out,
                                                   const unsigned int* __restrict__ ctr,
                                                   const int* __restrict__ list,
                                                   int cap) {
  __shared__ float xs[8][256];
  __shared__ float bv[256];
  __shared__ int   bix[256];
  const int tid = threadIdx.x;
  int n = (int)*ctr;
  if (n > cap) n = cap;
  const int nb = (n + 7) >> 3;
  for (int bb = blockIdx.x; bb < nb; bb += gridDim.x) {
    const int base = bb << 3;
    const int m = (n - base) < 8 ? (n - base) : 8;   // block-uniform
    int tb[8], tk[8];
#pragma unroll
    for (int tt = 0; tt < 8; ++tt) {
      if (tt < m) {
        int tok = list[base + tt];
        tb[tt] = tok >> 12; tk[tt] = tok & (TLEN - 1);
        xs[tt][tid] = x[(size_t)tb[tt] * NDIM * TLEN + (size_t)tid * TLEN + tk[tt]];
      }
    }
    __syncthreads();
    float btv[8]; int bti[8];
#pragma unroll
    for (int tt = 0; tt < 8; ++tt) { btv[tt] = __builtin_inff(); bti[tt] = 0; }
    for (int c4 = 0; c4 < 4; ++c4) {
      const float* et = embT + (size_t)(c4 * 256 + tid);
      float a[8];
#pragma unroll
      for (int tt = 0; tt < 8; ++tt) a[tt] = 0.0f;
      for (int k = 0; k < NDIM; ++k) {                // strict k-ascending chains
        float ev = et[(size_t)k * NCODE];
#pragma unroll
        for (int tt = 0; tt < 8; ++tt) a[tt] = fmaf(xs[tt][k], ev, a[tt]);
      }
#pragma unroll
      for (int tt = 0; tt < 8; ++tt) {
        float eu = 2.0f - 2.0f * a[tt];
        if (eu < btv[tt]) { btv[tt] = eu; bti[tt] = c4 * 256 + tid; }
      }
    }
#pragma unroll
    for (int tt = 0; tt < 8; ++tt) {
      if (tt < m) { bv[tid] = btv[tt]; bix[tid] = bti[tt]; }
      __syncthreads();
      if (tt < m) {
        for (int s = 128; s > 0; s >>= 1) {
          if (tid < s) {
            float ov = bv[tid + s]; int oi = bix[tid + s];
            if (ov < bv[tid] || (ov == bv[tid] && oi < bix[tid])) { bv[tid] = ov; bix[tid] = oi; }
          }
          __syncthreads();
        }
        const int best = bix[0];
        out[(size_t)tb[tt] * NDIM * TLEN + (size_t)tid * TLEN + tk[tt]] =
            emb[(size_t)best * NDIM + tid];
      }
      __syncthreads();
    }
  }
}

extern "C" void kernel_launch(void* const* d_in, const int* in_sizes, int n_in,
                              void* d_out, int out_size, void* d_ws, size_t ws_size,
                              hipStream_t stream) {
  (void)in_sizes; (void)n_in; (void)out_size;
  const float* x   = (const float*)d_in[0];
  const float* emb = (const float*)d_in[1];
  float* out = (float*)d_out;

  // ws layout: ehi 512KB | embT 1MB | ctr 16B | list
  unsigned short* ehi  = (unsigned short*)d_ws;
  float*          embT = (float*)((char*)d_ws + (size_t)512 * 1024);
  unsigned int*   ctr  = (unsigned int*)((char*)d_ws + (size_t)1536 * 1024);
  int*            lst  = (int*)((char*)ctr + 16);

  long avail = (long)ws_size - (long)1536 * 1024 - 16;
  int cap = avail > 0 ? (int)(avail / 4 < 65536 ? avail / 4 : 65536) : 0;

  svq_prep_emb<<<dim3(1024), dim3(256), 0, stream>>>(emb, ehi, embT, ctr);
  svq_main<<<dim3(NBATCH * (TLEN / BT)), dim3(256), 0, stream>>>(
      x, emb, (const short8*)ehi, out, ctr, lst, cap);
  svq_rescore<<<dim3(1024), dim3(256), 0, stream>>>(x, emb, embT, out, ctr, lst, cap);
}

// Round 9
// 222.640 us; speedup vs baseline: 1.8495x; 1.1787x over previous
//
#include <hip/hip_runtime.h>
#include <math.h>

typedef __attribute__((ext_vector_type(8))) short short8;   // 8 bf16 in 4 VGPRs
typedef __attribute__((ext_vector_type(4))) float f32x4;

#define NCODE  1024
#define NDIM   256
#define TLEN   4096
#define NBATCH 16
#define BT     64
#define TAU    2.5e-2f

__device__ __forceinline__ unsigned short f2bf(float f) {
  unsigned int u = __float_as_uint(f);
  u += 0x7FFFu + ((u >> 16) & 1u);          // round-to-nearest-even
  return (unsigned short)(u >> 16);
}

// Pre-split codebook into bf16 (hi only) in MFMA A-fragment order, and emit
// emb^T (fp32 [dim][code]) for the coalesced exact rescore.
// ushort index = ((ct*8 + ks)*64 + lane)*8 + j
// where row = ct*16 + (lane&15), k = ks*32 + (lane>>4)*8 + j
__global__ __launch_bounds__(256) void svq_prep_emb(const float* __restrict__ emb,
                                                    unsigned short* __restrict__ ehi,
                                                    float* __restrict__ embT,
                                                    unsigned int* __restrict__ ctr) {
  if (blockIdx.x == 0 && threadIdx.x == 0) *ctr = 0u;   // reset tie-list each launch
  int tid  = blockIdx.x * 256 + threadIdx.x;   // 0 .. 262143
  int j    = tid & 7;
  int lane = (tid >> 3) & 63;
  int blk  = tid >> 9;                          // ct*8 + ks
  int ct   = blk >> 3, ks = blk & 7;
  int row  = (ct << 4) | (lane & 15);
  int k    = (ks << 5) | ((lane >> 4) << 3) | j;
  float f  = emb[row * NDIM + k];
  ehi[tid] = f2bf(f);
  embT[(size_t)k * NCODE + row] = f;
}

// One k-step, single-bf16, ci=4 blocking: 4 ds_read_b128 + 16 MFMA.
// A single-buffered, reloaded after the MFMAs. All indices compile-time
// constants (rule #20).
#define KSTEP(KS)                                                               \
  {                                                                             \
    const int kb0 = ((KS) * 32 + khalf) * 2;                                    \
    _Pragma("unroll")                                                           \
    for (int ti = 0; ti < 4; ++ti) {                                            \
      const int off = bbase + (kb0 ^ bswz) + ti * 8192;                         \
      short8 bh = *(const short8*)(xhi_s + off);                                \
      _Pragma("unroll")                                                         \
      for (int ci = 0; ci < 4; ++ci)                                            \
        acc[ci][ti] = __builtin_amdgcn_mfma_f32_16x16x32_bf16(ah[ci], bh, acc[ci][ti], 0, 0, 0); \
    }                                                                           \
    if ((KS) < 7) {                                                             \
      _Pragma("unroll")                                                         \
      for (int ci = 0; ci < 4; ++ci)                                            \
        ah[ci] = pe_h[(ci * 8 + (KS) + 1) * 64];                                \
    }                                                                           \
  }

// R7 proved amdgpu_waves_per_eu IS honored (R4/R8 showed __launch_bounds__ is
// taken as license to shrink VGPRs and spill). Pin exactly 4 waves/EU:
// VGPR budget 128 >= live set ~108 (acc 64 + ah 16 + transient B 4 + best 12
// + addressing ~12) -> no spill; 4 blocks/CU = grid 1024 / 256 CUs.
__global__
__attribute__((amdgpu_flat_work_group_size(256, 256), amdgpu_waves_per_eu(4, 4)))
void svq_main(const float* __restrict__ x,
              const float* __restrict__ emb,
              const short8* __restrict__ ehi,
              float* __restrict__ out,
              unsigned int* __restrict__ ctr,
              int* __restrict__ list,
              int cap) {
  __shared__ char smem[32768];   // x_hi [64 t][512 B]; reused by reduce+epilogue
  const int tid  = threadIdx.x;
  const int lane = tid & 63;
  const int w    = tid >> 6;                 // wave id 0..3
  const int bx   = blockIdx.x;
  const int b    = bx >> 6;                  // batch
  const int t0   = (bx & 63) * BT;           // token-tile start

  // ---- stage x tile into LDS: bf16 hi, t-major rows of k, XOR bank swizzle ----
  {
    const float* xb = x + (size_t)b * NDIM * TLEN + t0;
    const int tl = lane;
    const int sw = (tl & 7) << 4;
#pragma unroll 4
    for (int it = 0; it < 16; ++it) {
      const int kb = w * 4 + it * 16;
      float v0 = xb[(size_t)(kb + 0) * TLEN + tl];
      float v1 = xb[(size_t)(kb + 1) * TLEN + tl];
      float v2 = xb[(size_t)(kb + 2) * TLEN + tl];
      float v3 = xb[(size_t)(kb + 3) * TLEN + tl];
      unsigned short h0 = f2bf(v0), h1 = f2bf(v1), h2 = f2bf(v2), h3 = f2bf(v3);
      unsigned long long ph = (unsigned long long)h0 | ((unsigned long long)h1 << 16)
                            | ((unsigned long long)h2 << 32) | ((unsigned long long)h3 << 48);
      *(unsigned long long*)(smem + tl * 512 + ((kb * 2) ^ sw)) = ph;
    }
  }
  __syncthreads();

  float bestv[4], secv[4];
  int   besti[4];
#pragma unroll
  for (int ti = 0; ti < 4; ++ti) {
    bestv[ti] = __builtin_inff(); secv[ti] = __builtin_inff(); besti[ti] = 0;
  }

  const char* xhi_s = smem;
  const int bbase = (lane & 15) * 512;        // t-row byte base (ti adds 8192)
  const int bswz  = (lane & 7) << 4;          // swizzle (ti*16 preserves t&7)
  const int khalf = (lane >> 4) << 3;         // k-subgroup within 32-k step

  // ---- main loop: wave w covers codes [w*256, w*256+256) in 4 chunks of 64 ----
  for (int cc = 0; cc < 4; ++cc) {
    const int ctb = w * 16 + cc * 4;          // base 16-code tile index
    const short8* pe_h = ehi + (size_t)ctb * 8 * 64 + lane;

    f32x4 acc[4][4];
#pragma unroll
    for (int ci = 0; ci < 4; ++ci)
#pragma unroll
      for (int ti = 0; ti < 4; ++ti)
        acc[ci][ti] = (f32x4){0.f, 0.f, 0.f, 0.f};

    short8 ah[4];
#pragma unroll
    for (int ci = 0; ci < 4; ++ci) ah[ci] = pe_h[ci * 8 * 64];

    KSTEP(0) KSTEP(1) KSTEP(2) KSTEP(3)
    KSTEP(4) KSTEP(5) KSTEP(6) KSTEP(7)

    // best + second-best of eu = 2 - 2*dot, ascending code order per lane
#pragma unroll
    for (int ci = 0; ci < 4; ++ci) {
      const int cbase = (ctb + ci) * 16 + ((lane >> 4) << 2);
#pragma unroll
      for (int j = 0; j < 4; ++j) {
#pragma unroll
        for (int ti = 0; ti < 4; ++ti) {
          float eu = fmaf(-2.0f, acc[ci][ti][j], 2.0f);
          if (eu < bestv[ti])      { secv[ti] = bestv[ti]; bestv[ti] = eu; besti[ti] = cbase + j; }
          else if (eu < secv[ti])  { secv[ti] = eu; }
        }
      }
    }
  }

  __syncthreads();   // all waves done with x LDS; reuse region below

  float* red_v = (float*)smem;
  float* red_s = (float*)(smem + 1024);
  int*   red_i = (int*)(smem + 2048);
  int*   idxf  = (int*)(smem + 3072);

  // cross-lane (code-row groups) reduce, merging (best, second), tie-break lower index
#pragma unroll
  for (int ti = 0; ti < 4; ++ti) {
    float v = bestv[ti], s = secv[ti]; int ix = besti[ti];
#pragma unroll
    for (int off = 16; off < 64; off <<= 1) {
      float ov = __shfl_xor(v, off);
      float os = __shfl_xor(s, off);
      int   oi = __shfl_xor(ix, off);
      if (ov < v || (ov == v && oi < ix)) { s = fminf(v, os); v = ov; ix = oi; }
      else                                { s = fminf(s, ov); }
    }
    if (lane < 16) {
      red_v[w * 64 + ti * 16 + lane] = v;
      red_s[w * 64 + ti * 16 + lane] = s;
      red_i[w * 64 + ti * 16 + lane] = ix;
    }
  }
  __syncthreads();
  if (tid < 64) {       // cross-wave reduce
    float v = red_v[tid], s = red_s[tid]; int ix = red_i[tid];
#pragma unroll
    for (int ww = 1; ww < 4; ++ww) {
      float ov = red_v[ww * 64 + tid], os = red_s[ww * 64 + tid];
      int   oi = red_i[ww * 64 + tid];
      if (ov < v || (ov == v && oi < ix)) { s = fminf(v, os); v = ov; ix = oi; }
      else                                { s = fminf(s, ov); }
    }
    idxf[tid] = ix;
    if (s - v < TAU) {   // near-tie: np-bit-replicated rescore will overwrite this token
      unsigned int slot = atomicAdd(ctr, 1u);
      if ((int)slot < cap) list[slot] = (b << 12) | (t0 + tid);
    }
  }
  __syncthreads();

  // ---- epilogue: winning emb rows via LDS (rotated), 2 dim-halves of 128 ----
  const int rt = tid >> 2, q = tid & 3;      // rt = token 0..63, q = quarter
  const int code = idxf[rt];
  __syncthreads();     // everyone has its code; safe to overwrite smem

  float* rows = (float*)smem;   // [64][128] f32, column rotated by +rt
  const float4* src = (const float4*)(emb + (size_t)code * NDIM);
  for (int h = 0; h < 2; ++h) {
#pragma unroll
    for (int i = 0; i < 8; ++i) {
      float4 v = src[h * 32 + q + 4 * i];
      int n = 4 * (q + 4 * i);               // 0..127 within half
      rows[rt * 128 + ((n + 0 + rt) & 127)] = v.x;
      rows[rt * 128 + ((n + 1 + rt) & 127)] = v.y;
      rows[rt * 128 + ((n + 2 + rt) & 127)] = v.z;
      rows[rt * 128 + ((n + 3 + rt) & 127)] = v.w;
    }
    __syncthreads();
    {
      float* op = out + (size_t)b * NDIM * TLEN + (size_t)h * 128 * TLEN + t0 + lane;
#pragma unroll 8
      for (int i = 0; i < 32; ++i) {
        int n = w * 32 + i;                  // 0..127 within half
        op[(size_t)n * TLEN] = rows[lane * 128 + ((n + lane) & 127)];
      }
    }
    __syncthreads();
  }
}

// Rescore near-tied tokens by BIT-REPLICATING the numpy fp32 reference:
// per (code, token), a SEQUENTIAL fp32 FMA chain over k ascending, then
// eu = 2.0f - 2.0f*acc, argmin first-min-wins (validated in R3). v3: loop
// reordered for throughput — per k-step, 4 coalesced embT loads feed 32
// independent FMA chains (8 tokens x 4 code-chunks); chain order per
// (code, token) is unchanged (k ascending), so numerics are bit-identical.
__global__ __launch_bounds__(256) void svq_rescore(const float* __restrict__ x,
                                                   const float* __restrict__ emb,
                                                   const float* __restrict__ embT,
                                                   float* __restrict__ out,
                                                   const unsigned int* __restrict__ ctr,
                                                   const int* __restrict__ list,
                                                   int cap) {
  __shared__ float xs[8][256];
  __shared__ float rv[8][4];
  __shared__ int   ri[8][4];
  __shared__ int   widx[8];
  const int tid  = threadIdx.x;
  const int lane = tid & 63;
  const int w    = tid >> 6;
  int n = (int)*ctr;
  if (n > cap) n = cap;
  const int nb = (n + 7) >> 3;
  for (int bb = blockIdx.x; bb < nb; bb += gridDim.x) {
    const int base = bb << 3;
    const int m = (n - base) < 8 ? (n - base) : 8;   // block-uniform, >=1
    int tb[8], tk[8];
#pragma unroll
    for (int tt = 0; tt < 8; ++tt) {
      int sl = tt < m ? tt : (m - 1);        // duplicate last token in dead slots
      int tok = list[base + sl];
      tb[tt] = tok >> 12; tk[tt] = tok & (TLEN - 1);
      xs[tt][tid] = x[(size_t)tb[tt] * NDIM * TLEN + (size_t)tid * TLEN + tk[tt]];
    }
    __syncthreads();

    float a[4][8];
#pragma unroll
    for (int c4 = 0; c4 < 4; ++c4)
#pragma unroll
      for (int tt = 0; tt < 8; ++tt) a[c4][tt] = 0.0f;

#pragma unroll 4
    for (int k = 0; k < NDIM; ++k) {
      float xv[8];
#pragma unroll
      for (int tt = 0; tt < 8; ++tt) xv[tt] = xs[tt][k];
#pragma unroll
      for (int c4 = 0; c4 < 4; ++c4) {
        float ev = embT[(size_t)k * NCODE + c4 * 256 + tid];
#pragma unroll
        for (int tt = 0; tt < 8; ++tt) a[c4][tt] = fmaf(xv[tt], ev, a[c4][tt]);
      }
    }

    float bt[8]; int bi[8];
#pragma unroll
    for (int tt = 0; tt < 8; ++tt) { bt[tt] = __builtin_inff(); bi[tt] = 0; }
#pragma unroll
    for (int c4 = 0; c4 < 4; ++c4) {         // ascending c4 = ascending code
#pragma unroll
      for (int tt = 0; tt < 8; ++tt) {
        float eu = 2.0f - 2.0f * a[c4][tt];
        if (eu < bt[tt]) { bt[tt] = eu; bi[tt] = c4 * 256 + tid; }
      }
    }

    // in-wave min+index reduce per token, then cross-wave via LDS
#pragma unroll
    for (int tt = 0; tt < 8; ++tt) {
      float v = bt[tt]; int ix = bi[tt];
#pragma unroll
      for (int off = 32; off >= 1; off >>= 1) {
        float ov = __shfl_xor(v, off);
        int   oi = __shfl_xor(ix, off);
        if (ov < v || (ov == v && oi < ix)) { v = ov; ix = oi; }
      }
      if (lane == 0) { rv[tt][w] = v; ri[tt][w] = ix; }
    }
    __syncthreads();
    if (tid < 8) {
      float v = rv[tid][0]; int ix = ri[tid][0];
#pragma unroll
      for (int ww = 1; ww < 4; ++ww) {
        float ov = rv[tid][ww]; int oi = ri[tid][ww];
        if (ov < v || (ov == v && oi < ix)) { v = ov; ix = oi; }
      }
      widx[tid] = ix;
    }
    __syncthreads();
#pragma unroll
    for (int tt = 0; tt < 8; ++tt) {
      if (tt < m)
        out[(size_t)tb[tt] * NDIM * TLEN + (size_t)tid * TLEN + tk[tt]] =
            emb[(size_t)widx[tt] * NDIM + tid];
    }
    __syncthreads();   // before next iteration overwrites xs/rv/ri/widx
  }
}

extern "C" void kernel_launch(void* const* d_in, const int* in_sizes, int n_in,
                              void* d_out, int out_size, void* d_ws, size_t ws_size,
                              hipStream_t stream) {
  (void)in_sizes; (void)n_in; (void)out_size;
  const float* x   = (const float*)d_in[0];
  const float* emb = (const float*)d_in[1];
  float* out = (float*)d_out;

  // ws layout: ehi 512KB | embT 1MB | ctr 16B | list
  unsigned short* ehi  = (unsigned short*)d_ws;
  float*          embT = (float*)((char*)d_ws + (size_t)512 * 1024);
  unsigned int*   ctr  = (unsigned int*)((char*)d_ws + (size_t)1536 * 1024);
  int*            lst  = (int*)((char*)ctr + 16);

  long avail = (long)ws_size - (long)1536 * 1024 - 16;
  int cap = avail > 0 ? (int)(avail / 4 < 65536 ? avail / 4 : 65536) : 0;

  svq_prep_emb<<<dim3(1024), dim3(256), 0, stream>>>(emb, ehi, embT, ctr);
  svq_main<<<dim3(NBATCH * (TLEN / BT)), dim3(256), 0, stream>>>(
      x, emb, (const short8*)ehi, out, ctr, lst, cap);
  svq_rescore<<<dim3(2048), dim3(256), 0, stream>>>(x, emb, embT, out, ctr, lst, cap);
}

// Round 10
// 130.014 us; speedup vs baseline: 3.1671x; 1.7124x over previous
//
#include <hip/hip_runtime.h>
#include <math.h>

typedef __attribute__((ext_vector_type(8))) short short8;   // 8 bf16 in 4 VGPRs
typedef __attribute__((ext_vector_type(4))) float f32x4;

#define NCODE  1024
#define NDIM   256
#define TLEN   4096
#define NBATCH 16
#define BT     64
#define TAU    2.5e-2f

__device__ __forceinline__ unsigned short f2bf(float f) {
  unsigned int u = __float_as_uint(f);
  u += 0x7FFFu + ((u >> 16) & 1u);          // round-to-nearest-even
  return (unsigned short)(u >> 16);
}

// Pre-split codebook into bf16 (hi only) in MFMA A-fragment order, and emit
// emb^T (fp32 [dim][code]) for the coalesced exact rescore.
// ushort index = ((ct*8 + ks)*64 + lane)*8 + j
// where row = ct*16 + (lane&15), k = ks*32 + (lane>>4)*8 + j
__global__ __launch_bounds__(256) void svq_prep_emb(const float* __restrict__ emb,
                                                    unsigned short* __restrict__ ehi,
                                                    float* __restrict__ embT,
                                                    unsigned int* __restrict__ ctr) {
  if (blockIdx.x == 0 && threadIdx.x == 0) *ctr = 0u;   // reset tie-list each launch
  int tid  = blockIdx.x * 256 + threadIdx.x;   // 0 .. 262143
  int j    = tid & 7;
  int lane = (tid >> 3) & 63;
  int blk  = tid >> 9;                          // ct*8 + ks
  int ct   = blk >> 3, ks = blk & 7;
  int row  = (ct << 4) | (lane & 15);
  int k    = (ks << 5) | ((lane >> 4) << 3) | j;
  float f  = emb[row * NDIM + k];
  ehi[tid] = f2bf(f);
  embT[(size_t)k * NCODE + row] = f;
}

// MFMA with accumulator FORCED into AGPRs ("+a"): asm operands cannot be
// spilled, so the R4-R9 allocator pathology (64-VGPR target + acc scratch
// round-trip) is structurally impossible. A/B stay in arch VGPRs.
#define MFMA_AGPR(ACC, A, B)                                                    \
  asm("v_mfma_f32_16x16x32_bf16 %0, %1, %2, %0" : "+a"(ACC) : "v"(A), "v"(B))

// One k-step, single-bf16, ci=4 blocking: 4 ds_read_b128 + 16 MFMA.
// A single-buffered, reloaded after the MFMAs. All indices compile-time
// constants (rule #20). Per-acc op order identical to R8/R9 (validated).
#define KSTEP(KS)                                                               \
  {                                                                             \
    const int kb0 = ((KS) * 32 + khalf) * 2;                                    \
    _Pragma("unroll")                                                           \
    for (int ti = 0; ti < 4; ++ti) {                                            \
      const int off = bbase + (kb0 ^ bswz) + ti * 8192;                         \
      short8 bh = *(const short8*)(xhi_s + off);                                \
      _Pragma("unroll")                                                         \
      for (int ci = 0; ci < 4; ++ci)                                            \
        MFMA_AGPR(acc[ci][ti], ah[ci], bh);                                     \
    }                                                                           \
    if ((KS) < 7) {                                                             \
      _Pragma("unroll")                                                         \
      for (int ci = 0; ci < 4; ++ci)                                            \
        ah[ci] = pe_h[(ci * 8 + (KS) + 1) * 64];                                \
    }                                                                           \
  }

// Arch live set ~55 VGPRs + 64 AGPR acc = 128 total/wave -> 4 waves/EU.
__global__
__attribute__((amdgpu_flat_work_group_size(256, 256)))
__attribute__((amdgpu_waves_per_eu(4, 4)))
void svq_main(const float* __restrict__ x,
              const float* __restrict__ emb,
              const short8* __restrict__ ehi,
              float* __restrict__ out,
              unsigned int* __restrict__ ctr,
              int* __restrict__ list,
              int cap) {
  __shared__ char smem[32768];   // x_hi [64 t][512 B]; reused by reduce+epilogue
  const int tid  = threadIdx.x;
  const int lane = tid & 63;
  const int w    = tid >> 6;                 // wave id 0..3
  const int bx   = blockIdx.x;
  const int b    = bx >> 6;                  // batch
  const int t0   = (bx & 63) * BT;           // token-tile start

  // ---- stage x tile into LDS: bf16 hi, t-major rows of k, XOR bank swizzle ----
  {
    const float* xb = x + (size_t)b * NDIM * TLEN + t0;
    const int tl = lane;
    const int sw = (tl & 7) << 4;
#pragma unroll 4
    for (int it = 0; it < 16; ++it) {
      const int kb = w * 4 + it * 16;
      float v0 = xb[(size_t)(kb + 0) * TLEN + tl];
      float v1 = xb[(size_t)(kb + 1) * TLEN + tl];
      float v2 = xb[(size_t)(kb + 2) * TLEN + tl];
      float v3 = xb[(size_t)(kb + 3) * TLEN + tl];
      unsigned short h0 = f2bf(v0), h1 = f2bf(v1), h2 = f2bf(v2), h3 = f2bf(v3);
      unsigned long long ph = (unsigned long long)h0 | ((unsigned long long)h1 << 16)
                            | ((unsigned long long)h2 << 32) | ((unsigned long long)h3 << 48);
      *(unsigned long long*)(smem + tl * 512 + ((kb * 2) ^ sw)) = ph;
    }
  }
  __syncthreads();

  float bestv[4], secv[4];
  int   besti[4];
#pragma unroll
  for (int ti = 0; ti < 4; ++ti) {
    bestv[ti] = __builtin_inff(); secv[ti] = __builtin_inff(); besti[ti] = 0;
  }

  const char* xhi_s = smem;
  const int bbase = (lane & 15) * 512;        // t-row byte base (ti adds 8192)
  const int bswz  = (lane & 7) << 4;          // swizzle (ti*16 preserves t&7)
  const int khalf = (lane >> 4) << 3;         // k-subgroup within 32-k step

  // ---- main loop: wave w covers codes [w*256, w*256+256) in 4 chunks of 64 ----
  for (int cc = 0; cc < 4; ++cc) {
    const int ctb = w * 16 + cc * 4;          // base 16-code tile index
    const short8* pe_h = ehi + (size_t)ctb * 8 * 64 + lane;

    f32x4 acc[4][4];
#pragma unroll
    for (int ci = 0; ci < 4; ++ci)
#pragma unroll
      for (int ti = 0; ti < 4; ++ti)
        acc[ci][ti] = (f32x4){0.f, 0.f, 0.f, 0.f};

    short8 ah[4];
#pragma unroll
    for (int ci = 0; ci < 4; ++ci) ah[ci] = pe_h[ci * 8 * 64];

    asm volatile("s_nop 1");   // VALU-write-AGPR -> MFMA-read-C wait states

    KSTEP(0) KSTEP(1) KSTEP(2) KSTEP(3)
    KSTEP(4) KSTEP(5) KSTEP(6) KSTEP(7)

    // MFMA-write-AGPR -> VALU(accvgpr_read) wait states
    asm volatile("s_nop 7\n\ts_nop 7\n\ts_nop 7");

    // best + second-best of eu = 2 - 2*dot, ascending code order per lane
#pragma unroll
    for (int ci = 0; ci < 4; ++ci) {
      const int cbase = (ctb + ci) * 16 + ((lane >> 4) << 2);
#pragma unroll
      for (int j = 0; j < 4; ++j) {
#pragma unroll
        for (int ti = 0; ti < 4; ++ti) {
          float eu = fmaf(-2.0f, acc[ci][ti][j], 2.0f);
          if (eu < bestv[ti])      { secv[ti] = bestv[ti]; bestv[ti] = eu; besti[ti] = cbase + j; }
          else if (eu < secv[ti])  { secv[ti] = eu; }
        }
      }
    }
  }

  __syncthreads();   // all waves done with x LDS; reuse region below

  float* red_v = (float*)smem;
  float* red_s = (float*)(smem + 1024);
  int*   red_i = (int*)(smem + 2048);
  int*   idxf  = (int*)(smem + 3072);

  // cross-lane (code-row groups) reduce, merging (best, second), tie-break lower index
#pragma unroll
  for (int ti = 0; ti < 4; ++ti) {
    float v = bestv[ti], s = secv[ti]; int ix = besti[ti];
#pragma unroll
    for (int off = 16; off < 64; off <<= 1) {
      float ov = __shfl_xor(v, off);
      float os = __shfl_xor(s, off);
      int   oi = __shfl_xor(ix, off);
      if (ov < v || (ov == v && oi < ix)) { s = fminf(v, os); v = ov; ix = oi; }
      else                                { s = fminf(s, ov); }
    }
    if (lane < 16) {
      red_v[w * 64 + ti * 16 + lane] = v;
      red_s[w * 64 + ti * 16 + lane] = s;
      red_i[w * 64 + ti * 16 + lane] = ix;
    }
  }
  __syncthreads();
  if (tid < 64) {       // cross-wave reduce
    float v = red_v[tid], s = red_s[tid]; int ix = red_i[tid];
#pragma unroll
    for (int ww = 1; ww < 4; ++ww) {
      float ov = red_v[ww * 64 + tid], os = red_s[ww * 64 + tid];
      int   oi = red_i[ww * 64 + tid];
      if (ov < v || (ov == v && oi < ix)) { s = fminf(v, os); v = ov; ix = oi; }
      else                                { s = fminf(s, ov); }
    }
    idxf[tid] = ix;
    if (s - v < TAU) {   // near-tie: np-bit-replicated rescore will overwrite this token
      unsigned int slot = atomicAdd(ctr, 1u);
      if ((int)slot < cap) list[slot] = (b << 12) | (t0 + tid);
    }
  }
  __syncthreads();

  // ---- epilogue: winning emb rows via LDS (rotated), 2 dim-halves of 128 ----
  const int rt = tid >> 2, q = tid & 3;      // rt = token 0..63, q = quarter
  const int code = idxf[rt];
  __syncthreads();     // everyone has its code; safe to overwrite smem

  float* rows = (float*)smem;   // [64][128] f32, column rotated by +rt
  const float4* src = (const float4*)(emb + (size_t)code * NDIM);
  for (int h = 0; h < 2; ++h) {
#pragma unroll
    for (int i = 0; i < 8; ++i) {
      float4 v = src[h * 32 + q + 4 * i];
      int n = 4 * (q + 4 * i);               // 0..127 within half
      rows[rt * 128 + ((n + 0 + rt) & 127)] = v.x;
      rows[rt * 128 + ((n + 1 + rt) & 127)] = v.y;
      rows[rt * 128 + ((n + 2 + rt) & 127)] = v.z;
      rows[rt * 128 + ((n + 3 + rt) & 127)] = v.w;
    }
    __syncthreads();
    {
      float* op = out + (size_t)b * NDIM * TLEN + (size_t)h * 128 * TLEN + t0 + lane;
#pragma unroll 8
      for (int i = 0; i < 32; ++i) {
        int n = w * 32 + i;                  // 0..127 within half
        op[(size_t)n * TLEN] = rows[lane * 128 + ((n + lane) & 127)];
      }
    }
    __syncthreads();
  }
}

// Rescore near-tied tokens by BIT-REPLICATING the numpy fp32 reference:
// per (code, token), a SEQUENTIAL fp32 FMA chain over k ascending, then
// eu = 2.0f - 2.0f*acc, argmin first-min-wins (validated in R3). Per k-step,
// 4 coalesced embT loads feed 32 independent FMA chains (8 tokens x 4
// code-chunks); chain order per (code, token) is k-ascending -> bit-identical.
__global__ __launch_bounds__(256) void svq_rescore(const float* __restrict__ x,
                                                   const float* __restrict__ emb,
                                                   const float* __restrict__ embT,
                                                   float* __restrict__ out,
                                                   const unsigned int* __restrict__ ctr,
                                                   const int* __restrict__ list,
                                                   int cap) {
  __shared__ float xs[8][256];
  __shared__ float rv[8][4];
  __shared__ int   ri[8][4];
  __shared__ int   widx[8];
  const int tid  = threadIdx.x;
  const int lane = tid & 63;
  const int w    = tid >> 6;
  int n = (int)*ctr;
  if (n > cap) n = cap;
  const int nb = (n + 7) >> 3;
  for (int bb = blockIdx.x; bb < nb; bb += gridDim.x) {
    const int base = bb << 3;
    const int m = (n - base) < 8 ? (n - base) : 8;   // block-uniform, >=1
    int tb[8], tk[8];
#pragma unroll
    for (int tt = 0; tt < 8; ++tt) {
      int sl = tt < m ? tt : (m - 1);        // duplicate last token in dead slots
      int tok = list[base + sl];
      tb[tt] = tok >> 12; tk[tt] = tok & (TLEN - 1);
      xs[tt][tid] = x[(size_t)tb[tt] * NDIM * TLEN + (size_t)tid * TLEN + tk[tt]];
    }
    __syncthreads();

    float a[4][8];
#pragma unroll
    for (int c4 = 0; c4 < 4; ++c4)
#pragma unroll
      for (int tt = 0; tt < 8; ++tt) a[c4][tt] = 0.0f;

#pragma unroll 4
    for (int k = 0; k < NDIM; ++k) {
      float xv[8];
#pragma unroll
      for (int tt = 0; tt < 8; ++tt) xv[tt] = xs[tt][k];
#pragma unroll
      for (int c4 = 0; c4 < 4; ++c4) {
        float ev = embT[(size_t)k * NCODE + c4 * 256 + tid];
#pragma unroll
        for (int tt = 0; tt < 8; ++tt) a[c4][tt] = fmaf(xv[tt], ev, a[c4][tt]);
      }
    }

    float bt[8]; int bi[8];
#pragma unroll
    for (int tt = 0; tt < 8; ++tt) { bt[tt] = __builtin_inff(); bi[tt] = 0; }
#pragma unroll
    for (int c4 = 0; c4 < 4; ++c4) {         // ascending c4 = ascending code
#pragma unroll
      for (int tt = 0; tt < 8; ++tt) {
        float eu = 2.0f - 2.0f * a[c4][tt];
        if (eu < bt[tt]) { bt[tt] = eu; bi[tt] = c4 * 256 + tid; }
      }
    }

    // in-wave min+index reduce per token, then cross-wave via LDS
#pragma unroll
    for (int tt = 0; tt < 8; ++tt) {
      float v = bt[tt]; int ix = bi[tt];
#pragma unroll
      for (int off = 32; off >= 1; off >>= 1) {
        float ov = __shfl_xor(v, off);
        int   oi = __shfl_xor(ix, off);
        if (ov < v || (ov == v && oi < ix)) { v = ov; ix = oi; }
      }
      if (lane == 0) { rv[tt][w] = v; ri[tt][w] = ix; }
    }
    __syncthreads();
    if (tid < 8) {
      float v = rv[tid][0]; int ix = ri[tid][0];
#pragma unroll
      for (int ww = 1; ww < 4; ++ww) {
        float ov = rv[tid][ww]; int oi = ri[tid][ww];
        if (ov < v || (ov == v && oi < ix)) { v = ov; ix = oi; }
      }
      widx[tid] = ix;
    }
    __syncthreads();
#pragma unroll
    for (int tt = 0; tt < 8; ++tt) {
      if (tt < m)
        out[(size_t)tb[tt] * NDIM * TLEN + (size_t)tid * TLEN + tk[tt]] =
            emb[(size_t)widx[tt] * NDIM + tid];
    }
    __syncthreads();   // before next iteration overwrites xs/rv/ri/widx
  }
}

extern "C" void kernel_launch(void* const* d_in, const int* in_sizes, int n_in,
                              void* d_out, int out_size, void* d_ws, size_t ws_size,
                              hipStream_t stream) {
  (void)in_sizes; (void)n_in; (void)out_size;
  const float* x   = (const float*)d_in[0];
  const float* emb = (const float*)d_in[1];
  float* out = (float*)d_out;

  // ws layout: ehi 512KB | embT 1MB | ctr 16B | list
  unsigned short* ehi  = (unsigned short*)d_ws;
  float*          embT = (float*)((char*)d_ws + (size_t)512 * 1024);
  unsigned int*   ctr  = (unsigned int*)((char*)d_ws + (size_t)1536 * 1024);
  int*            lst  = (int*)((char*)ctr + 16);

  long avail = (long)ws_size - (long)1536 * 1024 - 16;
  int cap = avail > 0 ? (int)(avail / 4 < 65536 ? avail / 4 : 65536) : 0;

  svq_prep_emb<<<dim3(1024), dim3(256), 0, stream>>>(emb, ehi, embT, ctr);
  svq_main<<<dim3(NBATCH * (TLEN / BT)), dim3(256), 0, stream>>>(
      x, emb, (const short8*)ehi, out, ctr, lst, cap);
  svq_rescore<<<dim3(2048), dim3(256), 0, stream>>>(x, emb, embT, out, ctr, lst, cap);
}